// Round 7
// baseline (122.286 us; speedup 1.0000x reference)
//
#include <hip/hip_runtime.h>
#include <math.h>
#include <float.h>

// b=8, c=64, H=W=64, KS=8 -> P = 57*57 = 3249.
// Stage 1 per (b,c): G[m,n] = <patch_m, patch_n> over P; corr = G/(sqrt(diag)sqrt(diag)P);
//   sort 64 m per column n desc; ranks {1,9,16,24,32,40,48,55,63} -> xp[b,c,576].
// Stage 2 per b: corr2[p,q] = sum_c Xn[c,p]Xn[c,q]/64; sort 576 p per q desc; 115 ranks.
//
// R12 lesson: 4th sort-side ablation in a row was neutral -> sort is NOT k3's
//   wall. R8's gain was the load-pattern fix, not the CE cut. Phase 1 issues
//   640 VMEM instrs/thread (the 9 "uniform" q-loads are per-lane vector loads,
//   not scalarized) -> ~25-30 us of VMEM issue.
// R13: q-panel (64 c x 9 q) preloaded into 9 VGPRs per wave (lane c holds
//   X[c][q0+qq]); c-loop feeds the shared operand via v_readlane (no memory op).
//   Per iter: 1 VMEM + 9 readlane + 10 FMA instead of 10 VMEM. FMA order over c
//   unchanged (bit-identical). Sort and k1 untouched.

#define IMGS 65

#if __has_builtin(__builtin_amdgcn_readlane)
#define RDLANE(x, l) __int_as_float(__builtin_amdgcn_readlane(__float_as_int(x), (l)))
#else
#define RDLANE(x, l) __shfl((x), (l), 64)
#endif

// ---- DPP helpers ----
template<int CTRL, int RM>
__device__ __forceinline__ float dpp_add(float x) {
    int o = __builtin_amdgcn_update_dpp(0, __float_as_int(x), CTRL, RM, 0xf, true);
    return x + __int_as_float(o);
}
__device__ __forceinline__ float wscan_add(float x) {
    x = dpp_add<0x111, 0xf>(x);
    x = dpp_add<0x112, 0xf>(x);
    x = dpp_add<0x114, 0xf>(x);
    x = dpp_add<0x118, 0xf>(x);
    x = dpp_add<0x142, 0xa>(x);
    x = dpp_add<0x143, 0xc>(x);
    return x;
}
template<int CTRL>
__device__ __forceinline__ float dpp_perm(float x) {
    int o = __builtin_amdgcn_update_dpp(__float_as_int(x), __float_as_int(x), CTRL, 0xf, 0xf, false);
    return __int_as_float(o);
}
#define QP_XOR1 0xB1   // [1,0,3,2]
#define QP_XOR2 0x4E   // [2,3,0,1]

// ---- xor-J lane exchange: DPP for 1/2 (VALU), ds_swizzle for 4/8/16, bpermute for 32 ----
template<int J>
__device__ __forceinline__ float shx(float x) {
    if constexpr (J == 1)       return dpp_perm<QP_XOR1>(x);
    else if constexpr (J == 2)  return dpp_perm<QP_XOR2>(x);
    else if constexpr (J <= 16)
        return __int_as_float(__builtin_amdgcn_ds_swizzle(__float_as_int(x), (J << 10) | 0x1F));
    else
        return __shfl_xor(x, 32, 64);
}

// in-lane compare-exchange between two regs; DESC: a (lower position) keeps max
template<int DESC>
__device__ __forceinline__ void cer(float& a, float& b) {
    const float mx = fmaxf(a, b), mn = fminf(a, b);
    if constexpr (DESC) { a = mx; b = mn; } else { a = mn; b = mx; }
}

// ---- batched bitonic stage with exec-branched select ----
// AM bit r set = reg r is an "ascending" slot (takes max when kma).
template<int KK, int J, int AM, int N>
__device__ __forceinline__ void sstage(float* v, const int lane) {
    float o[N];
    #pragma unroll
    for (int r = 0; r < N; ++r) o[r] = shx<J>(v[r]);
    const bool kma = (((lane & J) != 0) == ((lane & KK) == 0));
    if (kma) {
        #pragma unroll
        for (int r = 0; r < N; ++r) v[r] = ((AM >> r) & 1) ? fmaxf(v[r], o[r]) : fminf(v[r], o[r]);
    } else {
        #pragma unroll
        for (int r = 0; r < N; ++r) v[r] = ((AM >> r) & 1) ? fminf(v[r], o[r]) : fmaxf(v[r], o[r]);
    }
}
template<int AM, int N>
__device__ __forceinline__ void mergeL(float* v, const int lane) {
    sstage<0, 32, AM, N>(v, lane);
    sstage<0, 16, AM, N>(v, lane);
    sstage<0,  8, AM, N>(v, lane);
    sstage<0,  4, AM, N>(v, lane);
    sstage<0,  2, AM, N>(v, lane);
    sstage<0,  1, AM, N>(v, lane);
}

__host__ __device__ constexpr int offF(int dj) { return dj * (17 - dj) / 2; }       // 36 total
__host__ __device__ constexpr int offB(int dj) { return (dj - 1) * (16 - dj) / 2; } // 28 total

// ---------------- k1: fused stage-1, pair-symmetric, canonical-G ----------------
// grid = 512 (bc), block = 512 (8 waves; wave wv handles row-shift d = wv)
__global__ __launch_bounds__(512) void k1(const float* __restrict__ x,
                                          float* __restrict__ xp) {
    __shared__ float img[64 * IMGS];   // 16.6 KB
    __shared__ float G[64 * IMGS];     // canonical: G[m*65+n], m<=n

    const int t = threadIdx.x;
    const int bc = blockIdx.x;
    const float* src = x + (size_t)bc * 4096;

    #pragma unroll
    for (int k = 0; k < 2; ++k) {
        int i4 = t + k * 512;
        float4 v = ((const float4*)src)[i4];
        int fl = i4 * 4, row = fl >> 6, col = fl & 63;
        float* dd = &img[row * IMGS + col];
        dd[0] = v.x; dd[1] = v.y; dd[2] = v.z; dd[3] = v.w;
    }
    __syncthreads();

    const int wv = t >> 6, lane = t & 63;
    const int d = wv;                            // 0..7
    const int a = lane;
    const bool av = (a + d <= 63);
    const int a1 = min(a + d, 63);
    const float* r0 = &img[a * IMGS];
    const float* r1 = &img[a1 * IMGS];

    // ---- FMA phase: wf[k]=sum r0[u]*r1[u+k], wb[k]=sum r1[u]*r0[u+k]  (u=0..56) ----
    float wf[8] = {0,0,0,0,0,0,0,0}, wb[8] = {0,0,0,0,0,0,0,0};
    float sf[8], sb[8], hf[7], hb[7];
    #pragma unroll
    for (int k = 0; k < 7; ++k) { sf[k] = r1[k]; sb[k] = r0[k]; hf[k] = sf[k]; hb[k] = sb[k]; }
    #pragma unroll
    for (int c = 0; c < 7; ++c) {
        #pragma unroll
        for (int j = 0; j < 8; ++j) {
            const int u = c * 8 + j;
            sf[(j + 7) & 7] = r1[u + 7];
            sb[(j + 7) & 7] = r0[u + 7];
            const float f0 = sb[j & 7];          // r0[u]
            const float g0 = sf[j & 7];          // r1[u]
            #pragma unroll
            for (int k = 0; k < 8; ++k) wf[k] = fmaf(f0, sf[(j + k) & 7], wf[k]);
            #pragma unroll
            for (int k = 1; k < 8; ++k) wb[k] = fmaf(g0, sb[(j + k) & 7], wb[k]);
        }
    }
    {   // u = 56 (j-pattern 0)
        sf[7] = r1[63]; sb[7] = r0[63];
        const float f0 = sb[0], g0 = sf[0];
        #pragma unroll
        for (int k = 0; k < 8; ++k) wf[k] = fmaf(f0, sf[k], wf[k]);
        #pragma unroll
        for (int k = 1; k < 8; ++k) wb[k] = fmaf(g0, sb[k], wb[k]);
    }
    // now sf[k] = r1[56+k], sb[k] = r0[56+k]  (tails); hf/hb = heads

    // ---- slide over st (all indices compile-time) ----
    float Wf[36], Wb[28];
    #pragma unroll
    for (int dj = 0; dj < 8; ++dj) {
        float a0 = wf[dj];
        Wf[offF(dj)] = a0;
        #pragma unroll
        for (int st = 1; st < 8 - dj; ++st) {
            a0 += sb[st] * sf[st + dj] - hb[st - 1] * hf[st - 1 + dj];
            Wf[offF(dj) + st] = a0;
        }
    }
    #pragma unroll
    for (int dj = 1; dj < 8; ++dj) {
        float a0 = wb[dj];
        Wb[offB(dj)] = a0;
        #pragma unroll
        for (int st = 1; st < 8 - dj; ++st) {
            a0 += sf[st] * sb[st + dj] - hf[st - 1] * hb[st - 1 + dj];
            Wb[offB(dj) + st] = a0;
        }
    }

    // ---- mask invalid rows, DPP prefix-scan over lanes (rows a) ----
    const float msk = av ? 1.0f : 0.0f;
    #pragma unroll
    for (int i = 0; i < 36; ++i) Wf[i] = wscan_add(Wf[i] * msk);
    if (d > 0) {
        #pragma unroll
        for (int i = 0; i < 28; ++i) Wb[i] = wscan_add(Wb[i] * msk);
    }

    // ---- extract: S(ki) on lane ki+56 = P[lane] - P[lane-57]; write canonical G ----
    const bool wr = (lane >= 56) && (lane <= 63 - d);
    const int ki = lane - 56;
    #pragma unroll
    for (int dj = 0; dj < 8; ++dj) {
        #pragma unroll
        for (int st = 0; st < 8 - dj; ++st) {
            {
                float P = Wf[offF(dj) + st];
                float sl = __shfl_up(P, 57, 64);
                float S = P - (lane >= 57 ? sl : 0.0f);
                if (wr) G[(ki * 8 + st) * IMGS + ((ki + d) * 8 + st + dj)] = S;
            }
            if (d > 0 && dj > 0) {
                float P = Wb[offB(dj) + st];
                float sl = __shfl_up(P, 57, 64);
                float S = P - (lane >= 57 ? sl : 0.0f);
                if (wr) G[(ki * 8 + st + dj) * IMGS + ((ki + d) * 8 + st)] = S;
            }
        }
    }
    __syncthreads();

    // ---- normalize + batched sort64 (wave wv: columns wv*8..wv*8+7) ----
    const int m = lane;
    const float invm = 1.0f / fmaxf(sqrtf(G[m * 66]), 1e-12f);
    const float sc = 1.0f / 3249.0f;
    const int c0 = wv * 8;
    float v[8];
    #pragma unroll
    for (int cc = 0; cc < 8; ++cc) {
        const int col = c0 + cc;
        const int addr = (m <= col) ? m * IMGS + col : col * IMGS + m;   // symmetric read
        const float invc = __shfl(invm, col, 64);
        v[cc] = G[addr] * invm * invc * sc;
    }
    // sort64 descending over lanes, batched over 8 columns, exec-branched selects.
    sstage<2, 1, 0, 8>(v, lane);
    sstage<4, 2, 0, 8>(v, lane);   sstage<4, 1, 0, 8>(v, lane);
    sstage<8, 4, 0, 8>(v, lane);   sstage<8, 2, 0, 8>(v, lane);   sstage<8, 1, 0, 8>(v, lane);
    sstage<16, 8, 0, 8>(v, lane);  sstage<16, 4, 0, 8>(v, lane);  sstage<16, 2, 0, 8>(v, lane);
    sstage<16, 1, 0, 8>(v, lane);
    sstage<32, 16, 0, 8>(v, lane); sstage<32, 8, 0, 8>(v, lane);  sstage<32, 4, 0, 8>(v, lane);
    sstage<32, 2, 0, 8>(v, lane);  sstage<32, 1, 0, 8>(v, lane);
    sstage<64, 32, 0, 8>(v, lane); sstage<64, 16, 0, 8>(v, lane); sstage<64, 8, 0, 8>(v, lane);
    sstage<64, 4, 0, 8>(v, lane);  sstage<64, 2, 0, 8>(v, lane);  sstage<64, 1, 0, 8>(v, lane);
    // ranks2 = {1,9,16,24,32,40,48,55,63}
    int ridx = -1;
    if      (lane ==  1) ridx = 0; else if (lane ==  9) ridx = 1; else if (lane == 16) ridx = 2;
    else if (lane == 24) ridx = 3; else if (lane == 32) ridx = 4; else if (lane == 40) ridx = 5;
    else if (lane == 48) ridx = 6; else if (lane == 55) ridx = 7; else if (lane == 63) ridx = 8;
    if (ridx >= 0) {
        float* dst = xp + (size_t)bc * 576 + ridx * 64 + c0;
        *(float4*)&dst[0] = make_float4(v[0], v[1], v[2], v[3]);
        *(float4*)&dst[4] = make_float4(v[4], v[5], v[6], v[7]);
    }
}

// ---------------- k3: fused stage-2 (Gram columns + norms + sort + ranks) ----------------
// grid = 8*64 (b x q-group of 9), block = 576 (9 waves; wave sorts column q0+wv)
__global__ __launch_bounds__(576) void k3(const float* __restrict__ xp,
                                          float* __restrict__ out) {
    __shared__ __align__(16) float sbuf[9 * 580];   // raw corr columns, stride 580
    __shared__ __align__(16) float ipL[576];        // per-p inverse channel norms
    __shared__ float rankbuf[115 * 12];
    const int t = threadIdx.x;
    const int b = blockIdx.x >> 6, qg = blockIdx.x & 63;
    const int q0 = qg * 9;
    const float* __restrict__ xb = xp + (size_t)b * 36864;
    const int lane = t & 63;

    // ---- phase 1: thread p computes raw corr2 col entries for 9 q's + own norm ----
    // q-panel in registers: lane c holds xq[qq] = X[c][q0+qq]; c-loop reads it via
    // readlane (VALU) -> 1 VMEM + 9 readlane + 10 FMA per iter instead of 10 VMEM.
    {
        const int p = t;
        float xq[9];
        #pragma unroll
        for (int qq = 0; qq < 9; ++qq) xq[qq] = xb[lane * 576 + q0 + qq];
        float acc[9] = {0,0,0,0,0,0,0,0,0};
        float sd = 0.f;
        #pragma unroll
        for (int c = 0; c < 64; ++c) {
            const float xv = xb[c * 576 + p];                  // coalesced vector load
            sd = fmaf(xv, xv, sd);
            #pragma unroll
            for (int qq = 0; qq < 9; ++qq)
                acc[qq] = fmaf(xv, RDLANE(xq[qq], c), acc[qq]);
        }
        ipL[p] = 1.0f / fmaxf(sqrtf(sd), 1e-12f);
        #pragma unroll
        for (int qq = 0; qq < 9; ++qq) sbuf[qq * 580 + p] = acc[qq];
    }
    __syncthreads();

    // ---- phase 2: wave wv sorts column q = q0+wv, 9-reg merge-tree (no padding) ----
    const int wv = t >> 6;
    const float ipq = ipL[q0 + wv] * 0.015625f;   // /64 ; >0, order-preserving -> deferred
    float v[9];
    {
        const float* sb2 = &sbuf[wv * 580];
        #pragma unroll
        for (int r = 0; r < 9; ++r)
            v[r] = sb2[r * 64 + lane] * ipL[r * 64 + lane];   // stride-1: conflict-free
    }

    // level 0: per-reg 64-sorts; dirs: desc {0,3,5,6}, asc {1,2,4,7,8} -> AM=406
    constexpr int AM0 = (1<<1)|(1<<2)|(1<<4)|(1<<7)|(1<<8);   // 406
    sstage<2, 1, AM0, 9>(v, lane);
    sstage<4, 2, AM0, 9>(v, lane);   sstage<4, 1, AM0, 9>(v, lane);
    sstage<8, 4, AM0, 9>(v, lane);   sstage<8, 2, AM0, 9>(v, lane);   sstage<8, 1, AM0, 9>(v, lane);
    sstage<16, 8, AM0, 9>(v, lane);  sstage<16, 4, AM0, 9>(v, lane);  sstage<16, 2, AM0, 9>(v, lane);
    sstage<16, 1, AM0, 9>(v, lane);
    sstage<32, 16, AM0, 9>(v, lane); sstage<32, 8, AM0, 9>(v, lane);  sstage<32, 4, AM0, 9>(v, lane);
    sstage<32, 2, AM0, 9>(v, lane);  sstage<32, 1, AM0, 9>(v, lane);
    sstage<64, 32, AM0, 9>(v, lane); sstage<64, 16, AM0, 9>(v, lane); sstage<64, 8, AM0, 9>(v, lane);
    sstage<64, 4, AM0, 9>(v, lane);  sstage<64, 2, AM0, 9>(v, lane);  sstage<64, 1, AM0, 9>(v, lane);

    // level 1: (0,1)->desc128, (2,3)->asc128, (4,5)->asc128, (6,7)->desc128
    cer<1>(v[0], v[1]); cer<0>(v[2], v[3]); cer<0>(v[4], v[5]); cer<1>(v[6], v[7]);
    mergeL<(1<<2)|(1<<3)|(1<<4)|(1<<5), 8>(v, lane);   // asc regs 2..5

    // level 2: (0-3)->desc256, (4-7)->asc256
    cer<1>(v[0], v[2]); cer<1>(v[1], v[3]);
    cer<1>(v[0], v[1]); cer<1>(v[2], v[3]);
    cer<0>(v[4], v[6]); cer<0>(v[5], v[7]);
    cer<0>(v[4], v[5]); cer<0>(v[6], v[7]);
    mergeL<(1<<4)|(1<<5)|(1<<6)|(1<<7), 8>(v, lane);   // asc regs 4..7

    // level 3: (0-7)->desc512
    cer<1>(v[0], v[4]); cer<1>(v[1], v[5]); cer<1>(v[2], v[6]); cer<1>(v[3], v[7]);
    cer<1>(v[0], v[2]); cer<1>(v[1], v[3]); cer<1>(v[4], v[6]); cer<1>(v[5], v[7]);
    cer<1>(v[0], v[1]); cer<1>(v[2], v[3]); cer<1>(v[4], v[5]); cer<1>(v[6], v[7]);
    mergeL<0, 8>(v, lane);                             // all desc

    // level 4: desc512 + asc64(reg8) -> desc576 (virtual 1024 merge, -inf pads folded)
    cer<1>(v[7], v[8]);
    cer<1>(v[0], v[4]); cer<1>(v[1], v[5]); cer<1>(v[2], v[6]); cer<1>(v[3], v[7]);
    cer<1>(v[0], v[2]); cer<1>(v[1], v[3]); cer<1>(v[4], v[6]); cer<1>(v[5], v[7]);
    cer<1>(v[0], v[1]); cer<1>(v[2], v[3]); cer<1>(v[4], v[5]); cer<1>(v[6], v[7]);
    mergeL<0, 9>(v, lane);                             // all 9 regs, desc

    // ---- extract ranks = round(linspace(1,575,115)) == 1 + 5i + (2i)/57 + ((2i%57)>=29)
    #pragma unroll
    for (int r = 0; r < 9; ++r) {
        const int pos = r * 64 + lane;
        const int rr0 = (int)((float)pos * 0.1993f);
        #pragma unroll
        for (int dd = -1; dd <= 2; ++dd) {
            const int cand = rr0 + dd;
            if (cand >= 0 && cand < 115) {
                const int ti = 2 * cand;
                const int rk = 1 + 5 * cand + ti / 57 + ((ti % 57) >= 29 ? 1 : 0);
                if (rk == pos) rankbuf[cand * 12 + wv] = v[r] * ipq;
            }
        }
    }
    __syncthreads();
    for (int i = t; i < 115 * 9; i += 576) {
        const int rr = i / 9, qq = i - rr * 9;
        out[(size_t)b * 66240 + rr * 576 + q0 + qq] = rankbuf[rr * 12 + qq];
    }
}

extern "C" void kernel_launch(void* const* d_in, const int* in_sizes, int n_in,
                              void* d_out, int out_size, void* d_ws, size_t ws_size,
                              hipStream_t stream) {
    const float* x = (const float*)d_in[0];   // [8,64,64,64] fp32
    float* out = (float*)d_out;               // [8,115,24,24] fp32
    float* xp = (float*)d_ws;                 // [8,64,576] = 294912 floats (~1.2 MB)

    k1<<<dim3(512), dim3(512), 0, stream>>>(x, xp);
    k3<<<dim3(512), dim3(576), 0, stream>>>(xp, out);
}

// Round 8
// 120.246 us; speedup vs baseline: 1.0170x; 1.0170x over previous
//
#include <hip/hip_runtime.h>
#include <math.h>
#include <float.h>

// b=8, c=64, H=W=64, KS=8 -> P = 57*57 = 3249.
// Stage 1 per (b,c): G[m,n] = <patch_m, patch_n> over P; corr = G/(sqrt(diag)sqrt(diag)P);
//   sort 64 m per column n desc; ranks {1,9,16,24,32,40,48,55,63} -> xp[b,c,576].
// Stage 2 per b: corr2[p,q] = sum_c Xn[c,p]Xn[c,q]/64; sort 576 p per q desc; 115 ranks.
//
// R13 lesson: readlane REGRESSED k3 (phase-1 loads were L1-hit+hidden; added VALU
//   pressure). R11 arithmetic: sort-only kernel was ~35 us -> sort is the wall,
//   but not via CE count/selects/pipe-choice. Remaining terms: per-CU LDS-pipe
//   throughput (~216 LDS ops/column-sort) and 9-wave-block packing (<=3 blocks/CU,
//   34% occupancy, phase lockstep).
// R14: (1) k3 -> 192-thread 3-column blocks (grid 8x192, ~10 blocks/CU): cross-
//   block phase stagger; norms from k2, folded into sbuf store. (2) J=4/J=8
//   exchanges -> verified DPP forms (R9 encodings); J=16/32 stay on LDS pipe.
//   Sort network itself unchanged (R6-verified). k1 untouched.

#define IMGS 65

// ---- DPP helpers ----
template<int CTRL, int RM>
__device__ __forceinline__ float dpp_add(float x) {
    int o = __builtin_amdgcn_update_dpp(0, __float_as_int(x), CTRL, RM, 0xf, true);
    return x + __int_as_float(o);
}
__device__ __forceinline__ float wscan_add(float x) {
    x = dpp_add<0x111, 0xf>(x);
    x = dpp_add<0x112, 0xf>(x);
    x = dpp_add<0x114, 0xf>(x);
    x = dpp_add<0x118, 0xf>(x);
    x = dpp_add<0x142, 0xa>(x);
    x = dpp_add<0x143, 0xc>(x);
    return x;
}
template<int CTRL>
__device__ __forceinline__ float dpp_perm(float x) {
    int o = __builtin_amdgcn_update_dpp(__float_as_int(x), __float_as_int(x), CTRL, 0xf, 0xf, false);
    return __int_as_float(o);
}
#define QP_XOR1 0xB1   // [1,0,3,2]
#define QP_XOR2 0x4E   // [2,3,0,1]

// ---- xor-J lane exchange. VD=false: DPP 1/2, ds_swizzle 4/8/16, bpermute 32 (k1).
// ---- VD=true: additionally J=4 (bank-masked row_shl/shr pair) and J=8 (row_ror:8)
// ---- on the VALU pipe (R9-verified encodings) to offload the LDS pipe (k3 sort).
template<int J, bool VD = false>
__device__ __forceinline__ float shx(float x) {
    if constexpr (J == 1)       return dpp_perm<QP_XOR1>(x);
    else if constexpr (J == 2)  return dpp_perm<QP_XOR2>(x);
    else if constexpr (J == 4 && VD) {
        int t0 = __builtin_amdgcn_update_dpp(0,  __float_as_int(x), 0x104, 0xf, 0x5, false);
        int t1 = __builtin_amdgcn_update_dpp(t0, __float_as_int(x), 0x114, 0xf, 0xA, false);
        return __int_as_float(t1);
    }
    else if constexpr (J == 8 && VD) {
        int t = __builtin_amdgcn_update_dpp(0, __float_as_int(x), 0x128, 0xf, 0xf, false);
        return __int_as_float(t);
    }
    else if constexpr (J <= 16)
        return __int_as_float(__builtin_amdgcn_ds_swizzle(__float_as_int(x), (J << 10) | 0x1F));
    else
        return __shfl_xor(x, 32, 64);
}

// in-lane compare-exchange between two regs; DESC: a (lower position) keeps max
template<int DESC>
__device__ __forceinline__ void cer(float& a, float& b) {
    const float mx = fmaxf(a, b), mn = fminf(a, b);
    if constexpr (DESC) { a = mx; b = mn; } else { a = mn; b = mx; }
}

// ---- batched bitonic stage with exec-branched select ----
// AM bit r set = reg r is an "ascending" slot (takes max when kma).
template<int KK, int J, int AM, int N, bool VD = false>
__device__ __forceinline__ void sstage(float* v, const int lane) {
    float o[N];
    #pragma unroll
    for (int r = 0; r < N; ++r) o[r] = shx<J, VD>(v[r]);
    const bool kma = (((lane & J) != 0) == ((lane & KK) == 0));
    if (kma) {
        #pragma unroll
        for (int r = 0; r < N; ++r) v[r] = ((AM >> r) & 1) ? fmaxf(v[r], o[r]) : fminf(v[r], o[r]);
    } else {
        #pragma unroll
        for (int r = 0; r < N; ++r) v[r] = ((AM >> r) & 1) ? fminf(v[r], o[r]) : fmaxf(v[r], o[r]);
    }
}
template<int AM, int N, bool VD = false>
__device__ __forceinline__ void mergeL(float* v, const int lane) {
    sstage<0, 32, AM, N, VD>(v, lane);
    sstage<0, 16, AM, N, VD>(v, lane);
    sstage<0,  8, AM, N, VD>(v, lane);
    sstage<0,  4, AM, N, VD>(v, lane);
    sstage<0,  2, AM, N, VD>(v, lane);
    sstage<0,  1, AM, N, VD>(v, lane);
}

__host__ __device__ constexpr int offF(int dj) { return dj * (17 - dj) / 2; }       // 36 total
__host__ __device__ constexpr int offB(int dj) { return (dj - 1) * (16 - dj) / 2; } // 28 total

// ---------------- k1: fused stage-1, pair-symmetric, canonical-G ----------------
// grid = 512 (bc), block = 512 (8 waves; wave wv handles row-shift d = wv)
__global__ __launch_bounds__(512) void k1(const float* __restrict__ x,
                                          float* __restrict__ xp) {
    __shared__ float img[64 * IMGS];   // 16.6 KB
    __shared__ float G[64 * IMGS];     // canonical: G[m*65+n], m<=n

    const int t = threadIdx.x;
    const int bc = blockIdx.x;
    const float* src = x + (size_t)bc * 4096;

    #pragma unroll
    for (int k = 0; k < 2; ++k) {
        int i4 = t + k * 512;
        float4 v = ((const float4*)src)[i4];
        int fl = i4 * 4, row = fl >> 6, col = fl & 63;
        float* dd = &img[row * IMGS + col];
        dd[0] = v.x; dd[1] = v.y; dd[2] = v.z; dd[3] = v.w;
    }
    __syncthreads();

    const int wv = t >> 6, lane = t & 63;
    const int d = wv;                            // 0..7
    const int a = lane;
    const bool av = (a + d <= 63);
    const int a1 = min(a + d, 63);
    const float* r0 = &img[a * IMGS];
    const float* r1 = &img[a1 * IMGS];

    // ---- FMA phase: wf[k]=sum r0[u]*r1[u+k], wb[k]=sum r1[u]*r0[u+k]  (u=0..56) ----
    float wf[8] = {0,0,0,0,0,0,0,0}, wb[8] = {0,0,0,0,0,0,0,0};
    float sf[8], sb[8], hf[7], hb[7];
    #pragma unroll
    for (int k = 0; k < 7; ++k) { sf[k] = r1[k]; sb[k] = r0[k]; hf[k] = sf[k]; hb[k] = sb[k]; }
    #pragma unroll
    for (int c = 0; c < 7; ++c) {
        #pragma unroll
        for (int j = 0; j < 8; ++j) {
            const int u = c * 8 + j;
            sf[(j + 7) & 7] = r1[u + 7];
            sb[(j + 7) & 7] = r0[u + 7];
            const float f0 = sb[j & 7];          // r0[u]
            const float g0 = sf[j & 7];          // r1[u]
            #pragma unroll
            for (int k = 0; k < 8; ++k) wf[k] = fmaf(f0, sf[(j + k) & 7], wf[k]);
            #pragma unroll
            for (int k = 1; k < 8; ++k) wb[k] = fmaf(g0, sb[(j + k) & 7], wb[k]);
        }
    }
    {   // u = 56 (j-pattern 0)
        sf[7] = r1[63]; sb[7] = r0[63];
        const float f0 = sb[0], g0 = sf[0];
        #pragma unroll
        for (int k = 0; k < 8; ++k) wf[k] = fmaf(f0, sf[k], wf[k]);
        #pragma unroll
        for (int k = 1; k < 8; ++k) wb[k] = fmaf(g0, sb[k], wb[k]);
    }
    // now sf[k] = r1[56+k], sb[k] = r0[56+k]  (tails); hf/hb = heads

    // ---- slide over st (all indices compile-time) ----
    float Wf[36], Wb[28];
    #pragma unroll
    for (int dj = 0; dj < 8; ++dj) {
        float a0 = wf[dj];
        Wf[offF(dj)] = a0;
        #pragma unroll
        for (int st = 1; st < 8 - dj; ++st) {
            a0 += sb[st] * sf[st + dj] - hb[st - 1] * hf[st - 1 + dj];
            Wf[offF(dj) + st] = a0;
        }
    }
    #pragma unroll
    for (int dj = 1; dj < 8; ++dj) {
        float a0 = wb[dj];
        Wb[offB(dj)] = a0;
        #pragma unroll
        for (int st = 1; st < 8 - dj; ++st) {
            a0 += sf[st] * sb[st + dj] - hf[st - 1] * hb[st - 1 + dj];
            Wb[offB(dj) + st] = a0;
        }
    }

    // ---- mask invalid rows, DPP prefix-scan over lanes (rows a) ----
    const float msk = av ? 1.0f : 0.0f;
    #pragma unroll
    for (int i = 0; i < 36; ++i) Wf[i] = wscan_add(Wf[i] * msk);
    if (d > 0) {
        #pragma unroll
        for (int i = 0; i < 28; ++i) Wb[i] = wscan_add(Wb[i] * msk);
    }

    // ---- extract: S(ki) on lane ki+56 = P[lane] - P[lane-57]; write canonical G ----
    const bool wr = (lane >= 56) && (lane <= 63 - d);
    const int ki = lane - 56;
    #pragma unroll
    for (int dj = 0; dj < 8; ++dj) {
        #pragma unroll
        for (int st = 0; st < 8 - dj; ++st) {
            {
                float P = Wf[offF(dj) + st];
                float sl = __shfl_up(P, 57, 64);
                float S = P - (lane >= 57 ? sl : 0.0f);
                if (wr) G[(ki * 8 + st) * IMGS + ((ki + d) * 8 + st + dj)] = S;
            }
            if (d > 0 && dj > 0) {
                float P = Wb[offB(dj) + st];
                float sl = __shfl_up(P, 57, 64);
                float S = P - (lane >= 57 ? sl : 0.0f);
                if (wr) G[(ki * 8 + st + dj) * IMGS + ((ki + d) * 8 + st)] = S;
            }
        }
    }
    __syncthreads();

    // ---- normalize + batched sort64 (wave wv: columns wv*8..wv*8+7) ----
    const int m = lane;
    const float invm = 1.0f / fmaxf(sqrtf(G[m * 66]), 1e-12f);
    const float sc = 1.0f / 3249.0f;
    const int c0 = wv * 8;
    float v[8];
    #pragma unroll
    for (int cc = 0; cc < 8; ++cc) {
        const int col = c0 + cc;
        const int addr = (m <= col) ? m * IMGS + col : col * IMGS + m;   // symmetric read
        const float invc = __shfl(invm, col, 64);
        v[cc] = G[addr] * invm * invc * sc;
    }
    // sort64 descending over lanes, batched over 8 columns, exec-branched selects.
    sstage<2, 1, 0, 8>(v, lane);
    sstage<4, 2, 0, 8>(v, lane);   sstage<4, 1, 0, 8>(v, lane);
    sstage<8, 4, 0, 8>(v, lane);   sstage<8, 2, 0, 8>(v, lane);   sstage<8, 1, 0, 8>(v, lane);
    sstage<16, 8, 0, 8>(v, lane);  sstage<16, 4, 0, 8>(v, lane);  sstage<16, 2, 0, 8>(v, lane);
    sstage<16, 1, 0, 8>(v, lane);
    sstage<32, 16, 0, 8>(v, lane); sstage<32, 8, 0, 8>(v, lane);  sstage<32, 4, 0, 8>(v, lane);
    sstage<32, 2, 0, 8>(v, lane);  sstage<32, 1, 0, 8>(v, lane);
    sstage<64, 32, 0, 8>(v, lane); sstage<64, 16, 0, 8>(v, lane); sstage<64, 8, 0, 8>(v, lane);
    sstage<64, 4, 0, 8>(v, lane);  sstage<64, 2, 0, 8>(v, lane);  sstage<64, 1, 0, 8>(v, lane);
    // ranks2 = {1,9,16,24,32,40,48,55,63}
    int ridx = -1;
    if      (lane ==  1) ridx = 0; else if (lane ==  9) ridx = 1; else if (lane == 16) ridx = 2;
    else if (lane == 24) ridx = 3; else if (lane == 32) ridx = 4; else if (lane == 40) ridx = 5;
    else if (lane == 48) ridx = 6; else if (lane == 55) ridx = 7; else if (lane == 63) ridx = 8;
    if (ridx >= 0) {
        float* dst = xp + (size_t)bc * 576 + ridx * 64 + c0;
        *(float4*)&dst[0] = make_float4(v[0], v[1], v[2], v[3]);
        *(float4*)&dst[4] = make_float4(v[4], v[5], v[6], v[7]);
    }
}

// ---------------- k2: per-(b,p) inverse channel norms ----------------
// grid = 8*9, block = 64; thread p sums x^2 over 64 channels (same FMA order)
__global__ __launch_bounds__(64) void k2(const float* __restrict__ xp,
                                         float* __restrict__ ipL) {
    const int b = blockIdx.x / 9, pg = blockIdx.x % 9;
    const int p = pg * 64 + threadIdx.x;
    const float* xb = xp + (size_t)b * 36864;
    float sd = 0.f;
    #pragma unroll 8
    for (int c = 0; c < 64; ++c) { const float v = xb[c * 576 + p]; sd = fmaf(v, v, sd); }
    ipL[b * 576 + p] = 1.0f / fmaxf(sqrtf(sd), 1e-12f);
}

// ---------------- k3: fused stage-2, 3-column 3-wave blocks ----------------
// grid = 8*192 (b x q-group of 3), block = 192 (3 waves; wave wv sorts col q0+wv)
__global__ __launch_bounds__(192) void k3(const float* __restrict__ xp,
                                          const float* __restrict__ ipL,
                                          float* __restrict__ out) {
    __shared__ __align__(16) float sbuf[3 * 580];   // normalized corr cols (ip_p folded)
    __shared__ float rankbuf[115 * 4];
    const int t = threadIdx.x;
    const int b = blockIdx.x / 192, qg = blockIdx.x % 192;
    const int q0 = qg * 3;
    const float* __restrict__ xb  = xp + (size_t)b * 36864;
    const float* __restrict__ ipb = ipL + b * 576;

    // ---- phase 1: thread t computes 3 p-rows (t, t+192, t+384) x 3 q-cols ----
    {
        float acc[3][3] = {{0,0,0},{0,0,0},{0,0,0}};
        #pragma unroll 8
        for (int c = 0; c < 64; ++c) {
            const float* rowc = xb + c * 576;
            const float xq0 = rowc[q0 + 0];
            const float xq1 = rowc[q0 + 1];
            const float xq2 = rowc[q0 + 2];
            #pragma unroll
            for (int pp = 0; pp < 3; ++pp) {
                const float xv = rowc[t + 192 * pp];           // coalesced
                acc[pp][0] = fmaf(xv, xq0, acc[pp][0]);
                acc[pp][1] = fmaf(xv, xq1, acc[pp][1]);
                acc[pp][2] = fmaf(xv, xq2, acc[pp][2]);
            }
        }
        #pragma unroll
        for (int pp = 0; pp < 3; ++pp) {
            const int p = t + 192 * pp;
            const float ip = ipb[p];                           // fold ip_p here
            #pragma unroll
            for (int qq = 0; qq < 3; ++qq) sbuf[qq * 580 + p] = acc[pp][qq] * ip;
        }
    }
    __syncthreads();

    // ---- phase 2: wave wv sorts column q0+wv, 9-reg merge-tree (VD sort: J=4/8 on VALU) ----
    const int wv = t >> 6, lane = t & 63;
    const float ipq = ipb[q0 + wv] * 0.015625f;   // /64 ; >0, order-preserving -> deferred
    float v[9];
    {
        const float* sb2 = &sbuf[wv * 580];
        #pragma unroll
        for (int r = 0; r < 9; ++r) v[r] = sb2[r * 64 + lane];   // stride-1: conflict-free
    }

    // level 0: per-reg 64-sorts; dirs: desc {0,3,5,6}, asc {1,2,4,7,8} -> AM=406
    constexpr int AM0 = (1<<1)|(1<<2)|(1<<4)|(1<<7)|(1<<8);   // 406
    sstage<2, 1, AM0, 9, true>(v, lane);
    sstage<4, 2, AM0, 9, true>(v, lane);   sstage<4, 1, AM0, 9, true>(v, lane);
    sstage<8, 4, AM0, 9, true>(v, lane);   sstage<8, 2, AM0, 9, true>(v, lane);
    sstage<8, 1, AM0, 9, true>(v, lane);
    sstage<16, 8, AM0, 9, true>(v, lane);  sstage<16, 4, AM0, 9, true>(v, lane);
    sstage<16, 2, AM0, 9, true>(v, lane);  sstage<16, 1, AM0, 9, true>(v, lane);
    sstage<32, 16, AM0, 9, true>(v, lane); sstage<32, 8, AM0, 9, true>(v, lane);
    sstage<32, 4, AM0, 9, true>(v, lane);  sstage<32, 2, AM0, 9, true>(v, lane);
    sstage<32, 1, AM0, 9, true>(v, lane);
    sstage<64, 32, AM0, 9, true>(v, lane); sstage<64, 16, AM0, 9, true>(v, lane);
    sstage<64, 8, AM0, 9, true>(v, lane);  sstage<64, 4, AM0, 9, true>(v, lane);
    sstage<64, 2, AM0, 9, true>(v, lane);  sstage<64, 1, AM0, 9, true>(v, lane);

    // level 1: (0,1)->desc128, (2,3)->asc128, (4,5)->asc128, (6,7)->desc128
    cer<1>(v[0], v[1]); cer<0>(v[2], v[3]); cer<0>(v[4], v[5]); cer<1>(v[6], v[7]);
    mergeL<(1<<2)|(1<<3)|(1<<4)|(1<<5), 8, true>(v, lane);   // asc regs 2..5

    // level 2: (0-3)->desc256, (4-7)->asc256
    cer<1>(v[0], v[2]); cer<1>(v[1], v[3]);
    cer<1>(v[0], v[1]); cer<1>(v[2], v[3]);
    cer<0>(v[4], v[6]); cer<0>(v[5], v[7]);
    cer<0>(v[4], v[5]); cer<0>(v[6], v[7]);
    mergeL<(1<<4)|(1<<5)|(1<<6)|(1<<7), 8, true>(v, lane);   // asc regs 4..7

    // level 3: (0-7)->desc512
    cer<1>(v[0], v[4]); cer<1>(v[1], v[5]); cer<1>(v[2], v[6]); cer<1>(v[3], v[7]);
    cer<1>(v[0], v[2]); cer<1>(v[1], v[3]); cer<1>(v[4], v[6]); cer<1>(v[5], v[7]);
    cer<1>(v[0], v[1]); cer<1>(v[2], v[3]); cer<1>(v[4], v[5]); cer<1>(v[6], v[7]);
    mergeL<0, 8, true>(v, lane);                             // all desc

    // level 4: desc512 + asc64(reg8) -> desc576 (virtual 1024 merge, -inf pads folded)
    cer<1>(v[7], v[8]);
    cer<1>(v[0], v[4]); cer<1>(v[1], v[5]); cer<1>(v[2], v[6]); cer<1>(v[3], v[7]);
    cer<1>(v[0], v[2]); cer<1>(v[1], v[3]); cer<1>(v[4], v[6]); cer<1>(v[5], v[7]);
    cer<1>(v[0], v[1]); cer<1>(v[2], v[3]); cer<1>(v[4], v[5]); cer<1>(v[6], v[7]);
    mergeL<0, 9, true>(v, lane);                             // all 9 regs, desc

    // ---- extract ranks = round(linspace(1,575,115)) == 1 + 5i + (2i)/57 + ((2i%57)>=29)
    #pragma unroll
    for (int r = 0; r < 9; ++r) {
        const int pos = r * 64 + lane;
        const int rr0 = (int)((float)pos * 0.1993f);
        #pragma unroll
        for (int dd = -1; dd <= 2; ++dd) {
            const int cand = rr0 + dd;
            if (cand >= 0 && cand < 115) {
                const int ti = 2 * cand;
                const int rk = 1 + 5 * cand + ti / 57 + ((ti % 57) >= 29 ? 1 : 0);
                if (rk == pos) rankbuf[cand * 4 + wv] = v[r] * ipq;
            }
        }
    }
    __syncthreads();
    for (int i = t; i < 115 * 3; i += 192) {
        const int rr = i / 3, qq = i - rr * 3;
        out[(size_t)b * 66240 + rr * 576 + q0 + qq] = rankbuf[rr * 4 + qq];
    }
}

extern "C" void kernel_launch(void* const* d_in, const int* in_sizes, int n_in,
                              void* d_out, int out_size, void* d_ws, size_t ws_size,
                              hipStream_t stream) {
    const float* x = (const float*)d_in[0];   // [8,64,64,64] fp32
    float* out = (float*)d_out;               // [8,115,24,24] fp32
    float* xp  = (float*)d_ws;                // [8,64,576] = 294912 floats
    float* ipL = xp + 294912;                 // [8,576]    = 4608 floats

    k1<<<dim3(512),  dim3(512), 0, stream>>>(x, xp);
    k2<<<dim3(72),   dim3(64),  0, stream>>>(xp, ipL);
    k3<<<dim3(1536), dim3(192), 0, stream>>>(xp, ipL, out);
}

// Round 9
// 113.778 us; speedup vs baseline: 1.0748x; 1.0568x over previous
//
#include <hip/hip_runtime.h>
#include <math.h>
#include <float.h>

// b=8, c=64, H=W=64, KS=8 -> P = 57*57 = 3249.
// Stage 1 per (b,c): G[m,n] = <patch_m, patch_n> over P; corr = G/(sqrt(diag)sqrt(diag)P);
//   sort 64 m per column n desc; ranks {1,9,16,24,32,40,48,55,63} -> xpT[b,576,64] (TRANSPOSED).
// Stage 2 per b: corr2[p,q] = sum_c Xn[c,p]Xn[c,q]/64; sort 576 p per q desc; 115 ranks.
//
// R14 lesson (+R9/R13 reconciliation): sort pipe-choice is irrelevant (all-VALU ==
//   LDS-mix == 41us) because phase 1 dominates k3: 640 VMEM instrs/wave + ~3 addr
//   VALU each ~= 25-30us of the 41. VALUBusy 56% @46.5us => ~6.5k VALU-ops/wave,
//   ~3k of them phase-1 bookkeeping.
// R15: transpose stage-1 output to xpT[b][p][c] (column contiguous). k3 phase 1:
//   16 float4 own-column loads (imm offsets) + 9x16 wave-uniform float4 q-panel
//   loads (scalarizable to s_load). ~40x fewer VMEM instrs, ~4x less addr VALU.
//   FMA c-order unchanged. Sort/extract/phase-2 byte-identical to R6-verified.

#define IMGS 65

// ---- DPP helpers ----
template<int CTRL, int RM>
__device__ __forceinline__ float dpp_add(float x) {
    int o = __builtin_amdgcn_update_dpp(0, __float_as_int(x), CTRL, RM, 0xf, true);
    return x + __int_as_float(o);
}
__device__ __forceinline__ float wscan_add(float x) {
    x = dpp_add<0x111, 0xf>(x);
    x = dpp_add<0x112, 0xf>(x);
    x = dpp_add<0x114, 0xf>(x);
    x = dpp_add<0x118, 0xf>(x);
    x = dpp_add<0x142, 0xa>(x);
    x = dpp_add<0x143, 0xc>(x);
    return x;
}
template<int CTRL>
__device__ __forceinline__ float dpp_perm(float x) {
    int o = __builtin_amdgcn_update_dpp(__float_as_int(x), __float_as_int(x), CTRL, 0xf, 0xf, false);
    return __int_as_float(o);
}
#define QP_XOR1 0xB1   // [1,0,3,2]
#define QP_XOR2 0x4E   // [2,3,0,1]

// ---- xor-J lane exchange: DPP for 1/2 (VALU), ds_swizzle for 4/8/16, bpermute for 32 ----
template<int J>
__device__ __forceinline__ float shx(float x) {
    if constexpr (J == 1)       return dpp_perm<QP_XOR1>(x);
    else if constexpr (J == 2)  return dpp_perm<QP_XOR2>(x);
    else if constexpr (J <= 16)
        return __int_as_float(__builtin_amdgcn_ds_swizzle(__float_as_int(x), (J << 10) | 0x1F));
    else
        return __shfl_xor(x, 32, 64);
}

// in-lane compare-exchange between two regs; DESC: a (lower position) keeps max
template<int DESC>
__device__ __forceinline__ void cer(float& a, float& b) {
    const float mx = fmaxf(a, b), mn = fminf(a, b);
    if constexpr (DESC) { a = mx; b = mn; } else { a = mn; b = mx; }
}

// ---- batched bitonic stage with exec-branched select ----
// AM bit r set = reg r is an "ascending" slot (takes max when kma).
template<int KK, int J, int AM, int N>
__device__ __forceinline__ void sstage(float* v, const int lane) {
    float o[N];
    #pragma unroll
    for (int r = 0; r < N; ++r) o[r] = shx<J>(v[r]);
    const bool kma = (((lane & J) != 0) == ((lane & KK) == 0));
    if (kma) {
        #pragma unroll
        for (int r = 0; r < N; ++r) v[r] = ((AM >> r) & 1) ? fmaxf(v[r], o[r]) : fminf(v[r], o[r]);
    } else {
        #pragma unroll
        for (int r = 0; r < N; ++r) v[r] = ((AM >> r) & 1) ? fminf(v[r], o[r]) : fmaxf(v[r], o[r]);
    }
}
template<int AM, int N>
__device__ __forceinline__ void mergeL(float* v, const int lane) {
    sstage<0, 32, AM, N>(v, lane);
    sstage<0, 16, AM, N>(v, lane);
    sstage<0,  8, AM, N>(v, lane);
    sstage<0,  4, AM, N>(v, lane);
    sstage<0,  2, AM, N>(v, lane);
    sstage<0,  1, AM, N>(v, lane);
}

__host__ __device__ constexpr int offF(int dj) { return dj * (17 - dj) / 2; }       // 36 total
__host__ __device__ constexpr int offB(int dj) { return (dj - 1) * (16 - dj) / 2; } // 28 total

// ---------------- k1: fused stage-1, pair-symmetric, canonical-G ----------------
// grid = 512 (bc), block = 512 (8 waves; wave wv handles row-shift d = wv)
// Output TRANSPOSED: xpT[b][feature p][channel c], feature column contiguous.
__global__ __launch_bounds__(512) void k1(const float* __restrict__ x,
                                          float* __restrict__ xpT) {
    __shared__ float img[64 * IMGS];   // 16.6 KB
    __shared__ float G[64 * IMGS];     // canonical: G[m*65+n], m<=n

    const int t = threadIdx.x;
    const int bc = blockIdx.x;
    const float* src = x + (size_t)bc * 4096;

    #pragma unroll
    for (int k = 0; k < 2; ++k) {
        int i4 = t + k * 512;
        float4 v = ((const float4*)src)[i4];
        int fl = i4 * 4, row = fl >> 6, col = fl & 63;
        float* dd = &img[row * IMGS + col];
        dd[0] = v.x; dd[1] = v.y; dd[2] = v.z; dd[3] = v.w;
    }
    __syncthreads();

    const int wv = t >> 6, lane = t & 63;
    const int d = wv;                            // 0..7
    const int a = lane;
    const bool av = (a + d <= 63);
    const int a1 = min(a + d, 63);
    const float* r0 = &img[a * IMGS];
    const float* r1 = &img[a1 * IMGS];

    // ---- FMA phase: wf[k]=sum r0[u]*r1[u+k], wb[k]=sum r1[u]*r0[u+k]  (u=0..56) ----
    float wf[8] = {0,0,0,0,0,0,0,0}, wb[8] = {0,0,0,0,0,0,0,0};
    float sf[8], sb[8], hf[7], hb[7];
    #pragma unroll
    for (int k = 0; k < 7; ++k) { sf[k] = r1[k]; sb[k] = r0[k]; hf[k] = sf[k]; hb[k] = sb[k]; }
    #pragma unroll
    for (int c = 0; c < 7; ++c) {
        #pragma unroll
        for (int j = 0; j < 8; ++j) {
            const int u = c * 8 + j;
            sf[(j + 7) & 7] = r1[u + 7];
            sb[(j + 7) & 7] = r0[u + 7];
            const float f0 = sb[j & 7];          // r0[u]
            const float g0 = sf[j & 7];          // r1[u]
            #pragma unroll
            for (int k = 0; k < 8; ++k) wf[k] = fmaf(f0, sf[(j + k) & 7], wf[k]);
            #pragma unroll
            for (int k = 1; k < 8; ++k) wb[k] = fmaf(g0, sb[(j + k) & 7], wb[k]);
        }
    }
    {   // u = 56 (j-pattern 0)
        sf[7] = r1[63]; sb[7] = r0[63];
        const float f0 = sb[0], g0 = sf[0];
        #pragma unroll
        for (int k = 0; k < 8; ++k) wf[k] = fmaf(f0, sf[k], wf[k]);
        #pragma unroll
        for (int k = 1; k < 8; ++k) wb[k] = fmaf(g0, sb[k], wb[k]);
    }
    // now sf[k] = r1[56+k], sb[k] = r0[56+k]  (tails); hf/hb = heads

    // ---- slide over st (all indices compile-time) ----
    float Wf[36], Wb[28];
    #pragma unroll
    for (int dj = 0; dj < 8; ++dj) {
        float a0 = wf[dj];
        Wf[offF(dj)] = a0;
        #pragma unroll
        for (int st = 1; st < 8 - dj; ++st) {
            a0 += sb[st] * sf[st + dj] - hb[st - 1] * hf[st - 1 + dj];
            Wf[offF(dj) + st] = a0;
        }
    }
    #pragma unroll
    for (int dj = 1; dj < 8; ++dj) {
        float a0 = wb[dj];
        Wb[offB(dj)] = a0;
        #pragma unroll
        for (int st = 1; st < 8 - dj; ++st) {
            a0 += sf[st] * sb[st + dj] - hf[st - 1] * hb[st - 1 + dj];
            Wb[offB(dj) + st] = a0;
        }
    }

    // ---- mask invalid rows, DPP prefix-scan over lanes (rows a) ----
    const float msk = av ? 1.0f : 0.0f;
    #pragma unroll
    for (int i = 0; i < 36; ++i) Wf[i] = wscan_add(Wf[i] * msk);
    if (d > 0) {
        #pragma unroll
        for (int i = 0; i < 28; ++i) Wb[i] = wscan_add(Wb[i] * msk);
    }

    // ---- extract: S(ki) on lane ki+56 = P[lane] - P[lane-57]; write canonical G ----
    const bool wr = (lane >= 56) && (lane <= 63 - d);
    const int ki = lane - 56;
    #pragma unroll
    for (int dj = 0; dj < 8; ++dj) {
        #pragma unroll
        for (int st = 0; st < 8 - dj; ++st) {
            {
                float P = Wf[offF(dj) + st];
                float sl = __shfl_up(P, 57, 64);
                float S = P - (lane >= 57 ? sl : 0.0f);
                if (wr) G[(ki * 8 + st) * IMGS + ((ki + d) * 8 + st + dj)] = S;
            }
            if (d > 0 && dj > 0) {
                float P = Wb[offB(dj) + st];
                float sl = __shfl_up(P, 57, 64);
                float S = P - (lane >= 57 ? sl : 0.0f);
                if (wr) G[(ki * 8 + st + dj) * IMGS + ((ki + d) * 8 + st)] = S;
            }
        }
    }
    __syncthreads();

    // ---- normalize + batched sort64 (wave wv: columns wv*8..wv*8+7) ----
    const int m = lane;
    const float invm = 1.0f / fmaxf(sqrtf(G[m * 66]), 1e-12f);
    const float sc = 1.0f / 3249.0f;
    const int c0 = wv * 8;
    float v[8];
    #pragma unroll
    for (int cc = 0; cc < 8; ++cc) {
        const int col = c0 + cc;
        const int addr = (m <= col) ? m * IMGS + col : col * IMGS + m;   // symmetric read
        const float invc = __shfl(invm, col, 64);
        v[cc] = G[addr] * invm * invc * sc;
    }
    // sort64 descending over lanes, batched over 8 columns, exec-branched selects.
    sstage<2, 1, 0, 8>(v, lane);
    sstage<4, 2, 0, 8>(v, lane);   sstage<4, 1, 0, 8>(v, lane);
    sstage<8, 4, 0, 8>(v, lane);   sstage<8, 2, 0, 8>(v, lane);   sstage<8, 1, 0, 8>(v, lane);
    sstage<16, 8, 0, 8>(v, lane);  sstage<16, 4, 0, 8>(v, lane);  sstage<16, 2, 0, 8>(v, lane);
    sstage<16, 1, 0, 8>(v, lane);
    sstage<32, 16, 0, 8>(v, lane); sstage<32, 8, 0, 8>(v, lane);  sstage<32, 4, 0, 8>(v, lane);
    sstage<32, 2, 0, 8>(v, lane);  sstage<32, 1, 0, 8>(v, lane);
    sstage<64, 32, 0, 8>(v, lane); sstage<64, 16, 0, 8>(v, lane); sstage<64, 8, 0, 8>(v, lane);
    sstage<64, 4, 0, 8>(v, lane);  sstage<64, 2, 0, 8>(v, lane);  sstage<64, 1, 0, 8>(v, lane);
    // ranks2 = {1,9,16,24,32,40,48,55,63}
    int ridx = -1;
    if      (lane ==  1) ridx = 0; else if (lane ==  9) ridx = 1; else if (lane == 16) ridx = 2;
    else if (lane == 24) ridx = 3; else if (lane == 32) ridx = 4; else if (lane == 40) ridx = 5;
    else if (lane == 48) ridx = 6; else if (lane == 55) ridx = 7; else if (lane == 63) ridx = 8;
    if (ridx >= 0) {
        // transposed scatter: feature f = ridx*64 + c0 + cc, channel = bc & 63
        const int b = bc >> 6, ch = bc & 63;
        float* dst = xpT + (size_t)b * 36864 + (size_t)(ridx * 64 + c0) * 64 + ch;
        #pragma unroll
        for (int cc = 0; cc < 8; ++cc) dst[cc * 64] = v[cc];
    }
}

// ---------------- k3: fused stage-2 (Gram columns + norms + sort + ranks) ----------------
// grid = 8*64 (b x q-group of 9), block = 576 (9 waves; wave sorts column q0+wv)
// Phase 1 reads TRANSPOSED xpT: own column = 16 float4 (imm offsets);
// q-panel = wave-uniform float4 loads (scalarizable). FMA c-order unchanged.
__global__ __launch_bounds__(576) void k3(const float* __restrict__ xpT,
                                          float* __restrict__ out) {
    __shared__ __align__(16) float sbuf[9 * 580];   // raw corr columns, stride 580
    __shared__ __align__(16) float ipL[576];        // per-p inverse channel norms
    __shared__ float rankbuf[115 * 12];
    const int t = threadIdx.x;
    const int b = blockIdx.x >> 6, qg = blockIdx.x & 63;
    const int q0 = qg * 9;
    const float* __restrict__ xb = xpT + (size_t)b * 36864;

    // ---- phase 1: thread p computes raw corr2 col entries for 9 q's + own norm ----
    {
        const int p = t;
        const float4* __restrict__ own4 = (const float4*)(xb + (size_t)p * 64);
        const float4* __restrict__ qp4  = (const float4*)(xb + (size_t)q0 * 64);  // uniform base
        float acc[9] = {0,0,0,0,0,0,0,0,0};
        float sd = 0.f;
        #pragma unroll
        for (int c4 = 0; c4 < 16; ++c4) {
            const float4 xv = own4[c4];                       // 1 VMEM, imm offset
            sd = fmaf(xv.x, xv.x, sd);
            sd = fmaf(xv.y, xv.y, sd);
            sd = fmaf(xv.z, xv.z, sd);
            sd = fmaf(xv.w, xv.w, sd);
            #pragma unroll
            for (int qq = 0; qq < 9; ++qq) {
                const float4 xq = qp4[qq * 16 + c4];          // wave-uniform -> s_load
                acc[qq] = fmaf(xv.x, xq.x, acc[qq]);
                acc[qq] = fmaf(xv.y, xq.y, acc[qq]);
                acc[qq] = fmaf(xv.z, xq.z, acc[qq]);
                acc[qq] = fmaf(xv.w, xq.w, acc[qq]);
            }
        }
        ipL[p] = 1.0f / fmaxf(sqrtf(sd), 1e-12f);
        #pragma unroll
        for (int qq = 0; qq < 9; ++qq) sbuf[qq * 580 + p] = acc[qq];
    }
    __syncthreads();

    // ---- phase 2: wave wv sorts column q = q0+wv, 9-reg merge-tree (no padding) ----
    const int wv = t >> 6, lane = t & 63;
    const float ipq = ipL[q0 + wv] * 0.015625f;   // /64 ; >0, order-preserving -> deferred
    float v[9];
    {
        const float* sb2 = &sbuf[wv * 580];
        #pragma unroll
        for (int r = 0; r < 9; ++r)
            v[r] = sb2[r * 64 + lane] * ipL[r * 64 + lane];   // stride-1: conflict-free
    }

    // level 0: per-reg 64-sorts; dirs: desc {0,3,5,6}, asc {1,2,4,7,8} -> AM=406
    constexpr int AM0 = (1<<1)|(1<<2)|(1<<4)|(1<<7)|(1<<8);   // 406
    sstage<2, 1, AM0, 9>(v, lane);
    sstage<4, 2, AM0, 9>(v, lane);   sstage<4, 1, AM0, 9>(v, lane);
    sstage<8, 4, AM0, 9>(v, lane);   sstage<8, 2, AM0, 9>(v, lane);   sstage<8, 1, AM0, 9>(v, lane);
    sstage<16, 8, AM0, 9>(v, lane);  sstage<16, 4, AM0, 9>(v, lane);  sstage<16, 2, AM0, 9>(v, lane);
    sstage<16, 1, AM0, 9>(v, lane);
    sstage<32, 16, AM0, 9>(v, lane); sstage<32, 8, AM0, 9>(v, lane);  sstage<32, 4, AM0, 9>(v, lane);
    sstage<32, 2, AM0, 9>(v, lane);  sstage<32, 1, AM0, 9>(v, lane);
    sstage<64, 32, AM0, 9>(v, lane); sstage<64, 16, AM0, 9>(v, lane); sstage<64, 8, AM0, 9>(v, lane);
    sstage<64, 4, AM0, 9>(v, lane);  sstage<64, 2, AM0, 9>(v, lane);  sstage<64, 1, AM0, 9>(v, lane);

    // level 1: (0,1)->desc128, (2,3)->asc128, (4,5)->asc128, (6,7)->desc128
    cer<1>(v[0], v[1]); cer<0>(v[2], v[3]); cer<0>(v[4], v[5]); cer<1>(v[6], v[7]);
    mergeL<(1<<2)|(1<<3)|(1<<4)|(1<<5), 8>(v, lane);   // asc regs 2..5

    // level 2: (0-3)->desc256, (4-7)->asc256
    cer<1>(v[0], v[2]); cer<1>(v[1], v[3]);
    cer<1>(v[0], v[1]); cer<1>(v[2], v[3]);
    cer<0>(v[4], v[6]); cer<0>(v[5], v[7]);
    cer<0>(v[4], v[5]); cer<0>(v[6], v[7]);
    mergeL<(1<<4)|(1<<5)|(1<<6)|(1<<7), 8>(v, lane);   // asc regs 4..7

    // level 3: (0-7)->desc512
    cer<1>(v[0], v[4]); cer<1>(v[1], v[5]); cer<1>(v[2], v[6]); cer<1>(v[3], v[7]);
    cer<1>(v[0], v[2]); cer<1>(v[1], v[3]); cer<1>(v[4], v[6]); cer<1>(v[5], v[7]);
    cer<1>(v[0], v[1]); cer<1>(v[2], v[3]); cer<1>(v[4], v[5]); cer<1>(v[6], v[7]);
    mergeL<0, 8>(v, lane);                             // all desc

    // level 4: desc512 + asc64(reg8) -> desc576 (virtual 1024 merge, -inf pads folded)
    cer<1>(v[7], v[8]);
    cer<1>(v[0], v[4]); cer<1>(v[1], v[5]); cer<1>(v[2], v[6]); cer<1>(v[3], v[7]);
    cer<1>(v[0], v[2]); cer<1>(v[1], v[3]); cer<1>(v[4], v[6]); cer<1>(v[5], v[7]);
    cer<1>(v[0], v[1]); cer<1>(v[2], v[3]); cer<1>(v[4], v[5]); cer<1>(v[6], v[7]);
    mergeL<0, 9>(v, lane);                             // all 9 regs, desc

    // ---- extract ranks = round(linspace(1,575,115)) == 1 + 5i + (2i)/57 + ((2i%57)>=29)
    #pragma unroll
    for (int r = 0; r < 9; ++r) {
        const int pos = r * 64 + lane;
        const int rr0 = (int)((float)pos * 0.1993f);
        #pragma unroll
        for (int dd = -1; dd <= 2; ++dd) {
            const int cand = rr0 + dd;
            if (cand >= 0 && cand < 115) {
                const int ti = 2 * cand;
                const int rk = 1 + 5 * cand + ti / 57 + ((ti % 57) >= 29 ? 1 : 0);
                if (rk == pos) rankbuf[cand * 12 + wv] = v[r] * ipq;
            }
        }
    }
    __syncthreads();
    for (int i = t; i < 115 * 9; i += 576) {
        const int rr = i / 9, qq = i - rr * 9;
        out[(size_t)b * 66240 + rr * 576 + q0 + qq] = rankbuf[rr * 12 + qq];
    }
}

extern "C" void kernel_launch(void* const* d_in, const int* in_sizes, int n_in,
                              void* d_out, int out_size, void* d_ws, size_t ws_size,
                              hipStream_t stream) {
    const float* x = (const float*)d_in[0];   // [8,64,64,64] fp32
    float* out = (float*)d_out;               // [8,115,24,24] fp32
    float* xpT = (float*)d_ws;                // [8,576,64] = 294912 floats (~1.2 MB)

    k1<<<dim3(512), dim3(512), 0, stream>>>(x, xpT);
    k3<<<dim3(512), dim3(576), 0, stream>>>(xpT, out);
}

// Round 10
// 111.138 us; speedup vs baseline: 1.1003x; 1.0238x over previous
//
#include <hip/hip_runtime.h>
#include <math.h>
#include <float.h>

// b=8, c=64, H=W=64, KS=8 -> P = 57*57 = 3249.
// Stage 1 per (b,c): G[m,n] = <patch_m, patch_n> over P; corr = G/(sqrt(diag)sqrt(diag)P);
//   sort 64 m per column n desc; ranks {1,9,16,24,32,40,48,55,63} -> xp[b,c,576].
// Stage 2 per b: corr2[p,q] = sum_c Xn[c,p]Xn[c,q]/64; sort 576 p per q desc; 115 ranks.
//
// R16: lock-in of the session-best configuration (R1, measured 111.1 us).
// Ledger: 8 structural variants (all-VALU exchanges, 2-col/wave ILP, GEMM+sort
//   kernel split, exec-branched selects, readlane q-panel, 3-wave occupancy
//   restructure, transposed layout) all measured 111-123 us. Decomposition:
//   harness fill ~41 us (268 MB poison, 81% HBM peak) + k1 ~29 us (VALU-issue-
//   bound ~85%) + k3 ~41 us (mixed issue/latency; invariant to exchange pipe
//   and +-30% op count at its fixed 18 waves/CU = one wave per sorted column).

#define IMGS 65

// ---- DPP helpers (compile-time ctrl via templates; LDS-pipe-free cross-lane) ----
template<int CTRL, int RM>
__device__ __forceinline__ float dpp_add(float x) {
    int o = __builtin_amdgcn_update_dpp(0, __float_as_int(x), CTRL, RM, 0xf, true);
    return x + __int_as_float(o);
}
// inclusive wave64 prefix sum: row_shr 1/2/4/8, then bcast15 (rows 1,3), bcast31 (rows 2,3)
__device__ __forceinline__ float wscan_add(float x) {
    x = dpp_add<0x111, 0xf>(x);
    x = dpp_add<0x112, 0xf>(x);
    x = dpp_add<0x114, 0xf>(x);
    x = dpp_add<0x118, 0xf>(x);
    x = dpp_add<0x142, 0xa>(x);
    x = dpp_add<0x143, 0xc>(x);
    return x;
}
template<int CTRL>
__device__ __forceinline__ float dpp_perm(float x) {
    int o = __builtin_amdgcn_update_dpp(__float_as_int(x), __float_as_int(x), CTRL, 0xf, 0xf, false);
    return __int_as_float(o);
}
// xor-1 / xor-2 within quads
#define QP_XOR1 0xB1   // [1,0,3,2]
#define QP_XOR2 0x4E   // [2,3,0,1]

// ---- xor-J lane exchange: DPP for 1/2 (VALU), ds_swizzle for 4/8/16 (LDS pipe),
// ---- ds_bpermute for 32. Mixed pipes = dual-issue headroom.
template<int J>
__device__ __forceinline__ float shx(float x) {
    if constexpr (J == 1)       return dpp_perm<QP_XOR1>(x);
    else if constexpr (J == 2)  return dpp_perm<QP_XOR2>(x);
    else if constexpr (J <= 16)
        return __int_as_float(__builtin_amdgcn_ds_swizzle(__float_as_int(x), (J << 10) | 0x1F));
    else
        return __shfl_xor(x, 32, 64);
}

template<int J>
__device__ __forceinline__ void cex(float& v, const bool keep_max) {
    const float o = shx<J>(v);
    v = keep_max ? fmaxf(v, o) : fminf(v, o);
}

// in-lane compare-exchange between two regs; DESC: a (lower position) keeps max
template<int DESC>
__device__ __forceinline__ void cer(float& a, float& b) {
    const float mx = fmaxf(a, b), mn = fminf(a, b);
    if constexpr (DESC) { a = mx; b = mn; } else { a = mn; b = mx; }
}

// bitonic merge of a 64-element bitonic sequence held across lanes in one reg
template<int DESC>
__device__ __forceinline__ void merge64(float& v, const int lane) {
    cex<32>(v, (((lane & 32) != 0) ^ DESC) != 0);
    cex<16>(v, (((lane & 16) != 0) ^ DESC) != 0);
    cex<8>(v,  (((lane &  8) != 0) ^ DESC) != 0);
    cex<4>(v,  (((lane &  4) != 0) ^ DESC) != 0);
    cex<2>(v,  (((lane &  2) != 0) ^ DESC) != 0);
    cex<1>(v,  (((lane &  1) != 0) ^ DESC) != 0);
}

__host__ __device__ constexpr int offF(int dj) { return dj * (17 - dj) / 2; }       // 36 total
__host__ __device__ constexpr int offB(int dj) { return (dj - 1) * (16 - dj) / 2; } // 28 total

// ---------------- k1: fused stage-1, pair-symmetric, canonical-G ----------------
// grid = 512 (bc), block = 512 (8 waves; wave wv handles row-shift d = wv)
__global__ __launch_bounds__(512) void k1(const float* __restrict__ x,
                                          float* __restrict__ xp) {
    __shared__ float img[64 * IMGS];   // 16.6 KB
    __shared__ float G[64 * IMGS];     // canonical: G[m*65+n], m<=n

    const int t = threadIdx.x;
    const int bc = blockIdx.x;
    const float* src = x + (size_t)bc * 4096;

    #pragma unroll
    for (int k = 0; k < 2; ++k) {
        int i4 = t + k * 512;
        float4 v = ((const float4*)src)[i4];
        int fl = i4 * 4, row = fl >> 6, col = fl & 63;
        float* dd = &img[row * IMGS + col];
        dd[0] = v.x; dd[1] = v.y; dd[2] = v.z; dd[3] = v.w;
    }
    __syncthreads();

    const int wv = t >> 6, lane = t & 63;
    const int d = wv;                            // 0..7
    const int a = lane;
    const bool av = (a + d <= 63);
    const int a1 = min(a + d, 63);
    const float* r0 = &img[a * IMGS];
    const float* r1 = &img[a1 * IMGS];

    // ---- FMA phase: wf[k]=sum r0[u]*r1[u+k], wb[k]=sum r1[u]*r0[u+k]  (u=0..56) ----
    float wf[8] = {0,0,0,0,0,0,0,0}, wb[8] = {0,0,0,0,0,0,0,0};
    float sf[8], sb[8], hf[7], hb[7];
    #pragma unroll
    for (int k = 0; k < 7; ++k) { sf[k] = r1[k]; sb[k] = r0[k]; hf[k] = sf[k]; hb[k] = sb[k]; }
    #pragma unroll
    for (int c = 0; c < 7; ++c) {
        #pragma unroll
        for (int j = 0; j < 8; ++j) {
            const int u = c * 8 + j;
            sf[(j + 7) & 7] = r1[u + 7];
            sb[(j + 7) & 7] = r0[u + 7];
            const float f0 = sb[j & 7];          // r0[u]
            const float g0 = sf[j & 7];          // r1[u]
            #pragma unroll
            for (int k = 0; k < 8; ++k) wf[k] = fmaf(f0, sf[(j + k) & 7], wf[k]);
            #pragma unroll
            for (int k = 1; k < 8; ++k) wb[k] = fmaf(g0, sb[(j + k) & 7], wb[k]);
        }
    }
    {   // u = 56 (j-pattern 0)
        sf[7] = r1[63]; sb[7] = r0[63];
        const float f0 = sb[0], g0 = sf[0];
        #pragma unroll
        for (int k = 0; k < 8; ++k) wf[k] = fmaf(f0, sf[k], wf[k]);
        #pragma unroll
        for (int k = 1; k < 8; ++k) wb[k] = fmaf(g0, sb[k], wb[k]);
    }
    // now sf[k] = r1[56+k], sb[k] = r0[56+k]  (tails); hf/hb = heads

    // ---- slide over st (all indices compile-time) ----
    float Wf[36], Wb[28];
    #pragma unroll
    for (int dj = 0; dj < 8; ++dj) {
        float a0 = wf[dj];
        Wf[offF(dj)] = a0;
        #pragma unroll
        for (int st = 1; st < 8 - dj; ++st) {
            a0 += sb[st] * sf[st + dj] - hb[st - 1] * hf[st - 1 + dj];
            Wf[offF(dj) + st] = a0;
        }
    }
    #pragma unroll
    for (int dj = 1; dj < 8; ++dj) {
        float a0 = wb[dj];
        Wb[offB(dj)] = a0;
        #pragma unroll
        for (int st = 1; st < 8 - dj; ++st) {
            a0 += sf[st] * sb[st + dj] - hf[st - 1] * hb[st - 1 + dj];
            Wb[offB(dj) + st] = a0;
        }
    }

    // ---- mask invalid rows, DPP prefix-scan over lanes (rows a) ----
    const float msk = av ? 1.0f : 0.0f;
    #pragma unroll
    for (int i = 0; i < 36; ++i) Wf[i] = wscan_add(Wf[i] * msk);
    if (d > 0) {
        #pragma unroll
        for (int i = 0; i < 28; ++i) Wb[i] = wscan_add(Wb[i] * msk);
    }

    // ---- extract: S(ki) on lane ki+56 = P[lane] - P[lane-57]; write canonical G ----
    const bool wr = (lane >= 56) && (lane <= 63 - d);
    const int ki = lane - 56;
    #pragma unroll
    for (int dj = 0; dj < 8; ++dj) {
        #pragma unroll
        for (int st = 0; st < 8 - dj; ++st) {
            {
                float P = Wf[offF(dj) + st];
                float sl = __shfl_up(P, 57, 64);
                float S = P - (lane >= 57 ? sl : 0.0f);
                if (wr) G[(ki * 8 + st) * IMGS + ((ki + d) * 8 + st + dj)] = S;
            }
            if (d > 0 && dj > 0) {
                float P = Wb[offB(dj) + st];
                float sl = __shfl_up(P, 57, 64);
                float S = P - (lane >= 57 ? sl : 0.0f);
                if (wr) G[(ki * 8 + st + dj) * IMGS + ((ki + d) * 8 + st)] = S;
            }
        }
    }
    __syncthreads();

    // ---- normalize + batched sort64 (wave wv: columns wv*8..wv*8+7) ----
    const int m = lane;
    const float invm = 1.0f / fmaxf(sqrtf(G[m * 66]), 1e-12f);
    const float sc = 1.0f / 3249.0f;
    const int c0 = wv * 8;
    float v[8];
    #pragma unroll
    for (int cc = 0; cc < 8; ++cc) {
        const int col = c0 + cc;
        const int addr = (m <= col) ? m * IMGS + col : col * IMGS + m;   // symmetric read
        const float invc = __shfl(invm, col, 64);
        v[cc] = G[addr] * invm * invc * sc;
    }
    #pragma unroll
    for (int kk = 2; kk <= 64; kk <<= 1) {
        #pragma unroll
        for (int j = kk >> 1; j > 0; j >>= 1) {
            const bool upper = (lane & j) != 0;
            const bool dir0  = (lane & kk) == 0;
            const bool keep_max = dir0 ^ upper;
            float o[8];
            #pragma unroll
            for (int cc = 0; cc < 8; ++cc) {
                if (j == 1)      o[cc] = dpp_perm<QP_XOR1>(v[cc]);
                else if (j == 2) o[cc] = dpp_perm<QP_XOR2>(v[cc]);
                else             o[cc] = __shfl_xor(v[cc], j, 64);
            }
            #pragma unroll
            for (int cc = 0; cc < 8; ++cc)
                v[cc] = keep_max ? fmaxf(v[cc], o[cc]) : fminf(v[cc], o[cc]);
        }
    }
    // ranks2 = {1,9,16,24,32,40,48,55,63}
    int ridx = -1;
    if      (lane ==  1) ridx = 0; else if (lane ==  9) ridx = 1; else if (lane == 16) ridx = 2;
    else if (lane == 24) ridx = 3; else if (lane == 32) ridx = 4; else if (lane == 40) ridx = 5;
    else if (lane == 48) ridx = 6; else if (lane == 55) ridx = 7; else if (lane == 63) ridx = 8;
    if (ridx >= 0) {
        float* dst = xp + (size_t)bc * 576 + ridx * 64 + c0;
        *(float4*)&dst[0] = make_float4(v[0], v[1], v[2], v[3]);
        *(float4*)&dst[4] = make_float4(v[4], v[5], v[6], v[7]);
    }
}

// ---------------- k3: fused stage-2 (Gram columns + norms + sort + ranks) ----------------
// grid = 8*64 (b x q-group of 9), block = 576 (9 waves; wave sorts column q0+wv)
__global__ __launch_bounds__(576) void k3(const float* __restrict__ xp,
                                          float* __restrict__ out) {
    __shared__ __align__(16) float sbuf[9 * 580];   // raw corr columns, stride 580
    __shared__ __align__(16) float ipL[576];        // per-p inverse channel norms
    __shared__ float rankbuf[115 * 12];
    const int t = threadIdx.x;
    const int b = blockIdx.x >> 6, qg = blockIdx.x & 63;
    const int q0 = qg * 9;
    const float* __restrict__ xb = xp + (size_t)b * 36864;

    // ---- phase 1: thread p computes raw corr2 col entries for 9 q's + own norm ----
    {
        const int p = t;
        float acc[9] = {0,0,0,0,0,0,0,0,0};
        float sd = 0.f;
        #pragma unroll 8
        for (int c = 0; c < 64; ++c) {
            const float xv = xb[c * 576 + p];                  // coalesced vector load
            sd = fmaf(xv, xv, sd);
            #pragma unroll
            for (int qq = 0; qq < 9; ++qq)
                acc[qq] = fmaf(xv, xb[c * 576 + q0 + qq], acc[qq]);  // uniform -> s_load
        }
        ipL[p] = 1.0f / fmaxf(sqrtf(sd), 1e-12f);
        #pragma unroll
        for (int qq = 0; qq < 9; ++qq) sbuf[qq * 580 + p] = acc[qq];
    }
    __syncthreads();

    // ---- phase 2: wave wv sorts column q = q0+wv, 9-reg merge-tree (no padding) ----
    const int wv = t >> 6, lane = t & 63;
    const float ipq = ipL[q0 + wv] * 0.015625f;   // /64 ; >0, order-preserving -> deferred
    float v[9];
    {
        const float* sb2 = &sbuf[wv * 580];
        #pragma unroll
        for (int r = 0; r < 9; ++r)
            v[r] = sb2[r * 64 + lane] * ipL[r * 64 + lane];   // stride-1: conflict-free
    }

    // level 0: per-reg 64-sorts; dirs: desc {0,3,5,6}, asc {1,2,4,7,8}
    #define SSTAGE(KK, J) { \
        const bool kma = (((lane & (J)) != 0) == ((lane & (KK)) == 0)); \
        cex<J>(v[0], !kma); cex<J>(v[1],  kma); cex<J>(v[2],  kma); cex<J>(v[3], !kma); \
        cex<J>(v[4],  kma); cex<J>(v[5], !kma); cex<J>(v[6], !kma); cex<J>(v[7],  kma); \
        cex<J>(v[8],  kma); }
    SSTAGE(2, 1)
    SSTAGE(4, 2)   SSTAGE(4, 1)
    SSTAGE(8, 4)   SSTAGE(8, 2)   SSTAGE(8, 1)
    SSTAGE(16, 8)  SSTAGE(16, 4)  SSTAGE(16, 2)  SSTAGE(16, 1)
    SSTAGE(32, 16) SSTAGE(32, 8)  SSTAGE(32, 4)  SSTAGE(32, 2)  SSTAGE(32, 1)
    SSTAGE(64, 32) SSTAGE(64, 16) SSTAGE(64, 8)  SSTAGE(64, 4)  SSTAGE(64, 2) SSTAGE(64, 1)
    #undef SSTAGE

    // level 1: (0,1)->desc128, (2,3)->asc128, (4,5)->asc128, (6,7)->desc128
    cer<1>(v[0], v[1]); cer<0>(v[2], v[3]); cer<0>(v[4], v[5]); cer<1>(v[6], v[7]);
    merge64<1>(v[0], lane); merge64<1>(v[1], lane);
    merge64<0>(v[2], lane); merge64<0>(v[3], lane);
    merge64<0>(v[4], lane); merge64<0>(v[5], lane);
    merge64<1>(v[6], lane); merge64<1>(v[7], lane);

    // level 2: (0-3)->desc256, (4-7)->asc256
    cer<1>(v[0], v[2]); cer<1>(v[1], v[3]);
    cer<1>(v[0], v[1]); cer<1>(v[2], v[3]);
    merge64<1>(v[0], lane); merge64<1>(v[1], lane); merge64<1>(v[2], lane); merge64<1>(v[3], lane);
    cer<0>(v[4], v[6]); cer<0>(v[5], v[7]);
    cer<0>(v[4], v[5]); cer<0>(v[6], v[7]);
    merge64<0>(v[4], lane); merge64<0>(v[5], lane); merge64<0>(v[6], lane); merge64<0>(v[7], lane);

    // level 3: (0-7)->desc512
    cer<1>(v[0], v[4]); cer<1>(v[1], v[5]); cer<1>(v[2], v[6]); cer<1>(v[3], v[7]);
    cer<1>(v[0], v[2]); cer<1>(v[1], v[3]); cer<1>(v[4], v[6]); cer<1>(v[5], v[7]);
    cer<1>(v[0], v[1]); cer<1>(v[2], v[3]); cer<1>(v[4], v[5]); cer<1>(v[6], v[7]);
    #pragma unroll
    for (int r = 0; r < 8; ++r) merge64<1>(v[r], lane);

    // level 4: desc512 + asc64(reg8) -> desc576 (virtual 1024 merge, -inf pads folded)
    cer<1>(v[7], v[8]);
    cer<1>(v[0], v[4]); cer<1>(v[1], v[5]); cer<1>(v[2], v[6]); cer<1>(v[3], v[7]);
    cer<1>(v[0], v[2]); cer<1>(v[1], v[3]); cer<1>(v[4], v[6]); cer<1>(v[5], v[7]);
    cer<1>(v[0], v[1]); cer<1>(v[2], v[3]); cer<1>(v[4], v[5]); cer<1>(v[6], v[7]);
    #pragma unroll
    for (int r = 0; r < 8; ++r) merge64<1>(v[r], lane);
    merge64<1>(v[8], lane);

    // ---- extract ranks = round(linspace(1,575,115)) == 1 + 5i + (2i)/57 + ((2i%57)>=29)
    #pragma unroll
    for (int r = 0; r < 9; ++r) {
        const int pos = r * 64 + lane;
        const int rr0 = (int)((float)pos * 0.1993f);
        #pragma unroll
        for (int dd = -1; dd <= 2; ++dd) {
            const int cand = rr0 + dd;
            if (cand >= 0 && cand < 115) {
                const int ti = 2 * cand;
                const int rk = 1 + 5 * cand + ti / 57 + ((ti % 57) >= 29 ? 1 : 0);
                if (rk == pos) rankbuf[cand * 12 + wv] = v[r] * ipq;
            }
        }
    }
    __syncthreads();
    for (int i = t; i < 115 * 9; i += 576) {
        const int rr = i / 9, qq = i - rr * 9;
        out[(size_t)b * 66240 + rr * 576 + q0 + qq] = rankbuf[rr * 12 + qq];
    }
}

extern "C" void kernel_launch(void* const* d_in, const int* in_sizes, int n_in,
                              void* d_out, int out_size, void* d_ws, size_t ws_size,
                              hipStream_t stream) {
    const float* x = (const float*)d_in[0];   // [8,64,64,64] fp32
    float* out = (float*)d_out;               // [8,115,24,24] fp32
    float* xp = (float*)d_ws;                 // [8,64,576] = 294912 floats (~1.2 MB)

    k1<<<dim3(512), dim3(512), 0, stream>>>(x, xp);
    k3<<<dim3(512), dim3(576), 0, stream>>>(xp, out);
}